// Round 1
// baseline (373.591 us; speedup 1.0000x reference)
//
#include <hip/hip_runtime.h>
#include <hip/hip_bf16.h>
#include <math.h>

#define B_SZ 8
#define SEQ 2048
#define DIM 512
#define TS 64
#define DC 128
#define LSTRIDE (DC + 8)   // bf16 elems; 272 B rows -> 2-way bank aliasing (free)

typedef __attribute__((ext_vector_type(8))) short bf16x8;
typedef __attribute__((ext_vector_type(4))) float f32x4;

__device__ __forceinline__ unsigned short f2bf(float f) {
    unsigned int u = __builtin_bit_cast(unsigned int, f);
    u += 0x7fffu + ((u >> 16) & 1u);   // RNE (NaN not expected in inputs)
    return (unsigned short)(u >> 16);
}

// Computes scaled logits (QK^T)/sqrt(SEQ) for causal-relevant 64x64 tiles only.
// Tiles strictly above the diagonal are never written (softmax kernel zeroes them).
__global__ __launch_bounds__(256)
void logits_kernel(const float* __restrict__ Q, const float* __restrict__ K,
                   float* __restrict__ out) {
    const int tk = blockIdx.x, tq = blockIdx.y, b = blockIdx.z;
    if (tk > tq) return;

    __shared__ __align__(16) unsigned short qs[TS * LSTRIDE];
    __shared__ __align__(16) unsigned short ks[TS * LSTRIDE];

    const int t = threadIdx.x;
    const int wave = t >> 6;
    const int lane = t & 63;
    const int l16 = lane & 15;
    const int quad = lane >> 4;

    const float* Qb = Q + ((size_t)b * SEQ + (size_t)tq * TS) * DIM;
    const float* Kb = K + ((size_t)b * SEQ + (size_t)tk * TS) * DIM;

    f32x4 acc[4];
#pragma unroll
    for (int i = 0; i < 4; i++) acc[i] = (f32x4){0.f, 0.f, 0.f, 0.f};

    for (int c = 0; c < DIM; c += DC) {
        __syncthreads();
        // stage TSxDC fp32 -> bf16 LDS for Q and K tiles
#pragma unroll
        for (int i = 0; i < (TS * DC / 4) / 256; i++) {
            int idx = t + i * 256;      // 0..2047
            int row = idx >> 5;         // / (DC/4)=32
            int c4  = idx & 31;
            float4 qv = *(const float4*)(Qb + row * DIM + c + c4 * 4);
            float4 kv = *(const float4*)(Kb + row * DIM + c + c4 * 4);
            ushort4 qh = { f2bf(qv.x), f2bf(qv.y), f2bf(qv.z), f2bf(qv.w) };
            ushort4 kh = { f2bf(kv.x), f2bf(kv.y), f2bf(kv.z), f2bf(kv.w) };
            *(ushort4*)&qs[row * LSTRIDE + c4 * 4] = qh;
            *(ushort4*)&ks[row * LSTRIDE + c4 * 4] = kh;
        }
        __syncthreads();
        // 4 K-dim steps of 32; each wave does 16 q-rows x 64 k-cols
#pragma unroll
        for (int d = 0; d < DC; d += 32) {
            bf16x8 afrag = *(const bf16x8*)&qs[(wave * 16 + l16) * LSTRIDE + d + quad * 8];
#pragma unroll
            for (int nt = 0; nt < 4; nt++) {
                bf16x8 bfrag = *(const bf16x8*)&ks[(nt * 16 + l16) * LSTRIDE + d + quad * 8];
                acc[nt] = __builtin_amdgcn_mfma_f32_16x16x32_bf16(afrag, bfrag, acc[nt], 0, 0, 0);
            }
        }
    }

    const float scale = 0.02209708691207961f;  // 1/sqrt(2048)
    float* outb = out + (size_t)b * SEQ * SEQ;
#pragma unroll
    for (int nt = 0; nt < 4; nt++) {
        int col = tk * TS + nt * 16 + l16;
#pragma unroll
        for (int r = 0; r < 4; r++) {
            int row = tq * TS + wave * 16 + quad * 4 + r;
            outb[(size_t)row * SEQ + col] = acc[nt][r] * scale;
        }
    }
}

// One block per output row: causal softmax in-place. k>q -> exactly 0.
__global__ __launch_bounds__(256)
void softmax_kernel(float* __restrict__ out) {
    const int q = blockIdx.x & (SEQ - 1);
    const int b = blockIdx.x >> 11;            // SEQ = 2^11
    float* row = out + ((size_t)b * SEQ + q) * SEQ;
    const int t = threadIdx.x;
    const int lane = t & 63;
    const int wave = t >> 6;
    const int n = q + 1;                       // valid prefix length

    __shared__ __align__(16) float sbuf[SEQ];
    __shared__ float red[8];

    float m = -INFINITY;
#pragma unroll
    for (int i = t; i < SEQ / 4; i += 256) {
        float4 v = *(const float4*)(row + i * 4);
        int k0 = i * 4;
        v.x = (k0 + 0 < n) ? v.x : -INFINITY;
        v.y = (k0 + 1 < n) ? v.y : -INFINITY;
        v.z = (k0 + 2 < n) ? v.z : -INFINITY;
        v.w = (k0 + 3 < n) ? v.w : -INFINITY;
        *(float4*)&sbuf[k0] = v;
        m = fmaxf(m, fmaxf(fmaxf(v.x, v.y), fmaxf(v.z, v.w)));
    }
#pragma unroll
    for (int off = 32; off > 0; off >>= 1) m = fmaxf(m, __shfl_down(m, off));
    if (lane == 0) red[wave] = m;
    __syncthreads();
    m = fmaxf(fmaxf(red[0], red[1]), fmaxf(red[2], red[3]));

    float s = 0.f;
#pragma unroll
    for (int i = t; i < SEQ / 4; i += 256) {
        int k0 = i * 4;
        float4 v = *(const float4*)&sbuf[k0];
        float4 e;
        e.x = __expf(v.x - m);
        e.y = __expf(v.y - m);
        e.z = __expf(v.z - m);
        e.w = __expf(v.w - m);
        *(float4*)&sbuf[k0] = e;
        s += e.x + e.y + e.z + e.w;
    }
#pragma unroll
    for (int off = 32; off > 0; off >>= 1) s += __shfl_down(s, off);
    if (lane == 0) red[4 + wave] = s;
    __syncthreads();
    s = red[4] + red[5] + red[6] + red[7];
    const float inv = 1.0f / s;

#pragma unroll
    for (int i = t; i < SEQ / 4; i += 256) {
        int k0 = i * 4;
        float4 e = *(const float4*)&sbuf[k0];
        e.x *= inv; e.y *= inv; e.z *= inv; e.w *= inv;
        *(float4*)(row + k0) = e;
    }
}

extern "C" void kernel_launch(void* const* d_in, const int* in_sizes, int n_in,
                              void* d_out, int out_size, void* d_ws, size_t ws_size,
                              hipStream_t stream) {
    // setup_inputs order: {"K": ..., "Q": ...}
    const float* Kp = (const float*)d_in[0];
    const float* Qp = (const float*)d_in[1];
    float* out = (float*)d_out;

    dim3 grid(SEQ / TS, SEQ / TS, B_SZ);   // (32, 32, 8); tk > tq blocks early-exit
    logits_kernel<<<grid, dim3(256), 0, stream>>>(Qp, Kp, out);
    softmax_kernel<<<dim3(B_SZ * SEQ), dim3(256), 0, stream>>>(out);
}

// Round 2
// 244.176 us; speedup vs baseline: 1.5300x; 1.5300x over previous
//
#include <hip/hip_runtime.h>
#include <hip/hip_bf16.h>
#include <math.h>

#define B_SZ 8
#define SEQ 2048
#define DIM 512

typedef __attribute__((ext_vector_type(8))) short bf16x8;
typedef __attribute__((ext_vector_type(8))) unsigned short u16x8;
typedef __attribute__((ext_vector_type(4))) float f32x4;

#define GLOBAL_AS __attribute__((address_space(1)))
#define LDS_AS __attribute__((address_space(3)))

__device__ __forceinline__ unsigned short f2bf(float f) {
    unsigned int u = __builtin_bit_cast(unsigned int, f);
    u += 0x7fffu + ((u >> 16) & 1u);   // RNE
    return (unsigned short)(u >> 16);
}

__device__ __forceinline__ void load_lds16(const void* g, void* l) {
    __builtin_amdgcn_global_load_lds((const GLOBAL_AS unsigned int*)g,
                                     (LDS_AS unsigned int*)l, 16, 0, 0);
}

// ---- fp32 -> bf16 conversion, 8 elems/thread ----
__global__ __launch_bounds__(256)
void convert_kernel(const float* __restrict__ src, unsigned short* __restrict__ dst) {
    int i = blockIdx.x * 256 + threadIdx.x;
    const float4* s = (const float4*)src;
    float4 a = s[2 * i];
    float4 b = s[2 * i + 1];
    u16x8 o;
    o[0] = f2bf(a.x); o[1] = f2bf(a.y); o[2] = f2bf(a.z); o[3] = f2bf(a.w);
    o[4] = f2bf(b.x); o[5] = f2bf(b.y); o[6] = f2bf(b.z); o[7] = f2bf(b.w);
    ((u16x8*)dst)[i] = o;
}

// ---- m97-structure NT GEMM: C = Q K^T * scale, 128x128 tile, BK=32 ----
#define BM 128
#define BK 32
__global__ __launch_bounds__(256)
void logits_mfma(const unsigned short* __restrict__ Qb, const unsigned short* __restrict__ Kb,
                 float* __restrict__ out) {
    const int tk = blockIdx.x, tq = blockIdx.y, b = blockIdx.z;
    if (tk > tq) return;

    __shared__ __align__(16) unsigned short a_lds[BM * BK];  // 8 KiB
    __shared__ __align__(16) unsigned short b_lds[BM * BK];  // 8 KiB

    const int t = threadIdx.x;
    const int wave = t >> 6;
    const int lane = t & 63;
    const int l16 = lane & 15;
    const int quad = lane >> 4;
    const int wm = wave >> 1;      // 2x2 wave grid, each wave 64x64
    const int wn = wave & 1;

    const unsigned short* Qrow = Qb + ((size_t)b * SEQ + (size_t)tq * BM) * DIM;
    const unsigned short* Krow = Kb + ((size_t)b * SEQ + (size_t)tk * BM) * DIM;

    // staging geometry: one global_load_lds = 64 lanes x 16B = 16 rows x 64B
    const int sr = lane >> 2;      // 0..15 row-within-instr
    const int kg = lane & 3;       // 0..3  k-group (8 bf16 each)

    f32x4 acc[4][4];
#pragma unroll
    for (int i = 0; i < 4; i++)
#pragma unroll
        for (int j = 0; j < 4; j++) acc[i][j] = (f32x4){0.f, 0.f, 0.f, 0.f};

    for (int k0 = 0; k0 < DIM; k0 += BK) {
#pragma unroll
        for (int j = wave; j < 8; j += 4) {
            int row = j * 16 + sr;
            load_lds16(Qrow + (size_t)row * DIM + k0 + kg * 8, &a_lds[(j * 16) * BK]);
            load_lds16(Krow + (size_t)row * DIM + k0 + kg * 8, &b_lds[(j * 16) * BK]);
        }
        __syncthreads();   // drains vmcnt (global_load_lds) + publishes LDS

        bf16x8 af[4], bf[4];
#pragma unroll
        for (int mi = 0; mi < 4; mi++)
            af[mi] = *(const bf16x8*)&a_lds[(wm * 64 + mi * 16 + l16) * BK + quad * 8];
#pragma unroll
        for (int ni = 0; ni < 4; ni++)
            bf[ni] = *(const bf16x8*)&b_lds[(wn * 64 + ni * 16 + l16) * BK + quad * 8];
#pragma unroll
        for (int mi = 0; mi < 4; mi++)
#pragma unroll
            for (int ni = 0; ni < 4; ni++)
                acc[mi][ni] = __builtin_amdgcn_mfma_f32_16x16x32_bf16(af[mi], bf[ni], acc[mi][ni], 0, 0, 0);
        __syncthreads();   // LDS reuse guard
    }

    const float scale = 0.02209708691207961f;  // 1/sqrt(2048)
    float* outb = out + (size_t)b * SEQ * SEQ;
#pragma unroll
    for (int mi = 0; mi < 4; mi++) {
#pragma unroll
        for (int ni = 0; ni < 4; ni++) {
            int col = tk * BM + wn * 64 + ni * 16 + l16;
#pragma unroll
            for (int r = 0; r < 4; r++) {
                int row = tq * BM + wm * 64 + mi * 16 + quad * 4 + r;
                outb[(size_t)row * SEQ + col] = acc[mi][ni][r] * scale;
            }
        }
    }
}

// ---- register-resident causal softmax: one block per row ----
__global__ __launch_bounds__(256)
void softmax_kernel(float* __restrict__ out) {
    const int q = blockIdx.x & (SEQ - 1);
    const int b = blockIdx.x >> 11;
    float* row = out + ((size_t)b * SEQ + q) * SEQ;
    const int t = threadIdx.x;
    const int lane = t & 63;
    const int wave = t >> 6;
    const int n = q + 1;

    __shared__ float red[8];

    float4 v[2];
    float m = -INFINITY;
#pragma unroll
    for (int j = 0; j < 2; j++) {
        int k0 = (t + j * 256) * 4;
        if (k0 < n) {
            float4 x = *(const float4*)(row + k0);
            x.y = (k0 + 1 < n) ? x.y : -INFINITY;
            x.z = (k0 + 2 < n) ? x.z : -INFINITY;
            x.w = (k0 + 3 < n) ? x.w : -INFINITY;
            v[j] = x;
            m = fmaxf(m, fmaxf(fmaxf(x.x, x.y), fmaxf(x.z, x.w)));
        } else {
            v[j] = (float4){-INFINITY, -INFINITY, -INFINITY, -INFINITY};
        }
    }
#pragma unroll
    for (int off = 1; off < 64; off <<= 1) m = fmaxf(m, __shfl_xor(m, off));
    if (lane == 0) red[wave] = m;
    __syncthreads();
    m = fmaxf(fmaxf(red[0], red[1]), fmaxf(red[2], red[3]));

    float s = 0.f;
#pragma unroll
    for (int j = 0; j < 2; j++) {
        float4 e;
        e.x = __expf(v[j].x - m);
        e.y = __expf(v[j].y - m);
        e.z = __expf(v[j].z - m);
        e.w = __expf(v[j].w - m);
        v[j] = e;
        s += e.x + e.y + e.z + e.w;
    }
#pragma unroll
    for (int off = 1; off < 64; off <<= 1) s += __shfl_xor(s, off);
    if (lane == 0) red[4 + wave] = s;
    __syncthreads();
    s = red[4] + red[5] + red[6] + red[7];
    const float inv = 1.0f / s;

#pragma unroll
    for (int j = 0; j < 2; j++) {
        int k0 = (t + j * 256) * 4;
        float4 e = v[j];
        e.x *= inv; e.y *= inv; e.z *= inv; e.w *= inv;
        *(float4*)(row + k0) = e;
    }
}

// ---- round-1 fallback logits kernel (used only if ws_size too small) ----
#define TS 64
#define DC 128
#define LSTRIDE (DC + 8)
__global__ __launch_bounds__(256)
void logits_fallback(const float* __restrict__ Q, const float* __restrict__ K,
                     float* __restrict__ out) {
    const int tk = blockIdx.x, tq = blockIdx.y, b = blockIdx.z;
    if (tk > tq) return;
    __shared__ __align__(16) unsigned short qs[TS * LSTRIDE];
    __shared__ __align__(16) unsigned short ks[TS * LSTRIDE];
    const int t = threadIdx.x;
    const int wave = t >> 6, lane = t & 63, l16 = lane & 15, quad = lane >> 4;
    const float* Qb = Q + ((size_t)b * SEQ + (size_t)tq * TS) * DIM;
    const float* Kb = K + ((size_t)b * SEQ + (size_t)tk * TS) * DIM;
    f32x4 acc[4];
#pragma unroll
    for (int i = 0; i < 4; i++) acc[i] = (f32x4){0.f, 0.f, 0.f, 0.f};
    for (int c = 0; c < DIM; c += DC) {
        __syncthreads();
#pragma unroll
        for (int i = 0; i < 8; i++) {
            int idx = t + i * 256;
            int row = idx >> 5, c4 = idx & 31;
            float4 qv = *(const float4*)(Qb + row * DIM + c + c4 * 4);
            float4 kv = *(const float4*)(Kb + row * DIM + c + c4 * 4);
            ushort4 qh = { f2bf(qv.x), f2bf(qv.y), f2bf(qv.z), f2bf(qv.w) };
            ushort4 kh = { f2bf(kv.x), f2bf(kv.y), f2bf(kv.z), f2bf(kv.w) };
            *(ushort4*)&qs[row * LSTRIDE + c4 * 4] = qh;
            *(ushort4*)&ks[row * LSTRIDE + c4 * 4] = kh;
        }
        __syncthreads();
#pragma unroll
        for (int d = 0; d < DC; d += 32) {
            bf16x8 afrag = *(const bf16x8*)&qs[(wave * 16 + l16) * LSTRIDE + d + quad * 8];
#pragma unroll
            for (int nt = 0; nt < 4; nt++) {
                bf16x8 bfrag = *(const bf16x8*)&ks[(nt * 16 + l16) * LSTRIDE + d + quad * 8];
                acc[nt] = __builtin_amdgcn_mfma_f32_16x16x32_bf16(afrag, bfrag, acc[nt], 0, 0, 0);
            }
        }
    }
    const float scale = 0.02209708691207961f;
    float* outb = out + (size_t)b * SEQ * SEQ;
#pragma unroll
    for (int nt = 0; nt < 4; nt++) {
        int col = tk * TS + nt * 16 + l16;
#pragma unroll
        for (int r = 0; r < 4; r++) {
            int row = tq * TS + wave * 16 + quad * 4 + r;
            outb[(size_t)row * SEQ + col] = acc[nt][r] * scale;
        }
    }
}

extern "C" void kernel_launch(void* const* d_in, const int* in_sizes, int n_in,
                              void* d_out, int out_size, void* d_ws, size_t ws_size,
                              hipStream_t stream) {
    // setup_inputs order: {"K": ..., "Q": ...}
    const float* Kp = (const float*)d_in[0];
    const float* Qp = (const float*)d_in[1];
    float* out = (float*)d_out;

    const size_t nElem = (size_t)B_SZ * SEQ * DIM;          // 8.4M per tensor
    if (ws_size >= 2 * nElem * sizeof(unsigned short)) {
        unsigned short* Qbf = (unsigned short*)d_ws;
        unsigned short* Kbf = Qbf + nElem;
        int cblocks = (int)(nElem / 8 / 256);               // 4096
        convert_kernel<<<dim3(cblocks), dim3(256), 0, stream>>>(Qp, Qbf);
        convert_kernel<<<dim3(cblocks), dim3(256), 0, stream>>>(Kp, Kbf);
        logits_mfma<<<dim3(SEQ / BM, SEQ / BM, B_SZ), dim3(256), 0, stream>>>(Qbf, Kbf, out);
    } else {
        logits_fallback<<<dim3(SEQ / TS, SEQ / TS, B_SZ), dim3(256), 0, stream>>>(Qp, Kp, out);
    }
    softmax_kernel<<<dim3(B_SZ * SEQ), dim3(256), 0, stream>>>(out);
}